// Round 2
// 402.958 us; speedup vs baseline: 1.1082x; 1.1082x over previous
//
#include <hip/hip_runtime.h>
#include <hip/hip_bf16.h>

#define B64   64
#define DH    512
#define HID   4096
#define VOC   50257
#define NSTEP 4
#define DHDH  (DH*DH)
#define NBLK_FUSED 64
#define HSZ   (B64*DH)

typedef __attribute__((ext_vector_type(8)))  short bf16x8;   // 8 bf16 = 4 VGPRs
typedef __attribute__((ext_vector_type(4)))  float f32x4;
typedef __attribute__((ext_vector_type(16))) float f32x16;
typedef __hip_bfloat16 bf16;

__device__ __forceinline__ bf16x8 ldg8(const bf16* p) {
    return *reinterpret_cast<const bf16x8*>(p);
}
__device__ __forceinline__ short f2bf(float x) {
    bf16 h = __float2bfloat16(x);
    return *reinterpret_cast<short*>(&h);
}
__device__ __forceinline__ bf16x8 cvt8(const float* p) {
    f32x4 a = *reinterpret_cast<const f32x4*>(p);
    f32x4 b = *reinterpret_cast<const f32x4*>(p + 4);
    bf16x8 r;
    r[0] = f2bf(a[0]); r[1] = f2bf(a[1]); r[2] = f2bf(a[2]); r[3] = f2bf(a[3]);
    r[4] = f2bf(b[0]); r[5] = f2bf(b[1]); r[6] = f2bf(b[2]); r[7] = f2bf(b[3]);
    return r;
}
__device__ __forceinline__ float sigmf(float x) { return 1.f / (1.f + __expf(-x)); }

// ---------------------------------------------------------------------------
// k_prep: convert ip_w, hs, 4 GRU weight matrices to bf16; gather embed rows
// for steps 1..3 as bf16. One 8-elem chunk per thread.
// ---------------------------------------------------------------------------
__global__ __launch_bounds__(512) void k_prep(
    const float* __restrict__ hs, const float* __restrict__ ipw,
    const float* __restrict__ wi0, const float* __restrict__ wh0,
    const float* __restrict__ wi1, const float* __restrict__ wh1,
    const float* __restrict__ embed, const int* __restrict__ tids,
    bf16* __restrict__ hsb, bf16* __restrict__ ipwb,
    bf16* __restrict__ w0i, bf16* __restrict__ w0h,
    bf16* __restrict__ w1i, bf16* __restrict__ w1h,
    bf16* __restrict__ xemb)
{
    int c = blockIdx.x * 512 + threadIdx.x;
    const float* src; bf16* dst;
    if      (c < 262144) { size_t t = c;           src = ipw + t*8; dst = ipwb + t*8; }
    else if (c < 294912) { size_t t = c - 262144;  src = hs  + t*8; dst = hsb  + t*8; }
    else if (c < 393216) { size_t t = c - 294912;  src = wi0 + t*8; dst = w0i + t*8; }
    else if (c < 491520) { size_t t = c - 393216;  src = wh0 + t*8; dst = w0h + t*8; }
    else if (c < 589824) { size_t t = c - 491520;  src = wi1 + t*8; dst = w1i + t*8; }
    else if (c < 688128) { size_t t = c - 589824;  src = wh1 + t*8; dst = w1h + t*8; }
    else {
        int t = c - 688128;              // 12288 chunks = 192 rows x 64 chunks
        int r = t >> 6, j = t & 63;      // r = (s-1)*64 + b
        int s = r >> 6, b = r & 63;
        int rid = tids[b * NSTEP + s];
        src = embed + (size_t)rid * DH + j * 8;
        dst = xemb  + (size_t)r   * DH + j * 8;
    }
    *reinterpret_cast<bf16x8*>(dst) = cvt8(src);
}

// ---------------------------------------------------------------------------
// grid-wide spin barrier (64 blocks x 8 waves, 32KB LDS -> all co-resident
// on 256 CUs; no occupancy limiter).
// ---------------------------------------------------------------------------
__device__ __forceinline__ void gridbar(int* bar, int phase) {
    __syncthreads();
    if (threadIdx.x == 0) {
        __threadfence();
        __hip_atomic_fetch_add(&bar[phase], 1, __ATOMIC_RELEASE, __HIP_MEMORY_SCOPE_AGENT);
        while (__hip_atomic_load(&bar[phase], __ATOMIC_ACQUIRE, __HIP_MEMORY_SCOPE_AGENT) < NBLK_FUSED)
            __builtin_amdgcn_s_sleep(8);
        __threadfence();
    }
    __syncthreads();
}

// K-split reduction buffer helpers. Layout red[vec][wave][r][lane]:
// scalar writes/reads are bank = lane%32 -> conflict-free.
__device__ __forceinline__ void red_store(float (*red)[8][4][64], int v, int w, int lane, f32x4 a) {
    red[v][w][0][lane] = a[0]; red[v][w][1][lane] = a[1];
    red[v][w][2][lane] = a[2]; red[v][w][3][lane] = a[3];
}
__device__ __forceinline__ float red_sum(float (*red)[8][4][64], int v, int wb, int kc, int lane) {
    return red[v][wb][kc][lane] + red[v][wb+1][kc][lane]
         + red[v][wb+2][kc][lane] + red[v][wb+3][kc][lane];
}

// ---------------------------------------------------------------------------
// k_fused v2: 64 blocks x 512 threads = 512 waves.
// Block = (d-tile, m-half); wave = (m-tile, kc) with kc = K-split of 4x128.
// Phase 0: ip-proj (K=4096, kc slice 1024) + precompute gi0 = x_s @ w_ih0^T
// for s=1..3 (off critical path; results live in registers of the epilogue
// thread). Then 8 dependent phases with grid barriers; per phase each wave
// does only 12-24 MFMA and 16-32 independent 16B loads.
// f32 GRU state h0/h1 lives in registers (thread owns element [row][d]).
// ---------------------------------------------------------------------------
__global__ __launch_bounds__(512) void k_fused(
    const bf16* __restrict__ hsb, const bf16* __restrict__ ipwb, const float* __restrict__ ipb,
    const bf16* __restrict__ w0i, const bf16* __restrict__ w0h,
    const float* __restrict__ bi0, const float* __restrict__ bh0,
    const bf16* __restrict__ w1i, const bf16* __restrict__ w1h,
    const float* __restrict__ bi1, const float* __restrict__ bh1,
    const bf16* __restrict__ xemb,
    bf16* __restrict__ h0b, bf16* __restrict__ h1b,
    bf16* __restrict__ hbig, int* __restrict__ bar)
{
    __shared__ float red[4][8][4][64];   // 32 KB
    int w = threadIdx.x >> 6, lane = threadIdx.x & 63;
    int lr = lane & 15, q = lane >> 4;
    int dt = blockIdx.x >> 1;            // d-tile 0..31
    int mh = blockIdx.x & 1;             // m-half
    int mt = mh * 2 + (w >> 2);          // m-tile 0..3
    int kc = w & 3;                      // K-split slice
    int wb = w & 4;                      // first wave id of my tile group
    int m0 = mt * 16, d0 = dt * 16;
    int d  = d0 + lr;
    int row = m0 + q * 4 + kc;           // epilogue-owned output row

    // biases in registers
    float bR0  = bi0[d] + bh0[d];
    float bZ0  = bi0[DH + d] + bh0[DH + d];
    float biN0 = bi0[2*DH + d], bhN0 = bh0[2*DH + d];
    float bR1  = bi1[d] + bh1[d];
    float bZ1  = bi1[DH + d] + bh1[DH + d];
    float biN1 = bi1[2*DH + d], bhN1 = bh1[2*DH + d];

    // ---- P0a: h0 = hs @ ip_w^T + ip_b  (K=4096, kc slice of 1024)
    float h0st, h1st;
    {
        const bf16* arow = hsb  + (size_t)(m0 + lr) * HID + kc * 1024 + q * 8;
        const bf16* brow = ipwb + (size_t)(d0 + lr) * HID + kc * 1024 + q * 8;
        f32x4 acc = {0,0,0,0};
#pragma unroll 8
        for (int k0 = 0; k0 < 1024; k0 += 32)
            acc = __builtin_amdgcn_mfma_f32_16x16x32_bf16(ldg8(arow + k0), ldg8(brow + k0), acc, 0, 0, 0);
        red_store(red, 0, w, lane, acc);
        __syncthreads();
        float S = red_sum(red, 0, wb, kc, lane);
        __syncthreads();
        float v = S + ipb[d];
        h0st = v; h1st = v;
        bf16 vb = __float2bfloat16(v);
        h0b[row * DH + d] = vb;
        h1b[row * DH + d] = vb;
    }

    // ---- P0b: gi0_s = x_s @ w_ih0^T for s=1..3 (s=0 has x=0), kept in regs
    float giR[NSTEP], giZ[NSTEP], giN[NSTEP];
    giR[0] = 0.f; giZ[0] = 0.f; giN[0] = 0.f;
#pragma unroll
    for (int s = 1; s < NSTEP; ++s) {
        const bf16* xr  = xemb + ((size_t)(s - 1) * B64 + m0 + lr) * DH + kc * 128 + q * 8;
        const bf16* wiR = w0i  + (size_t)(d0 + lr) * DH + kc * 128 + q * 8;
        f32x4 aR = {0,0,0,0}, aZ = {0,0,0,0}, aN = {0,0,0,0};
#pragma unroll
        for (int k0 = 0; k0 < 128; k0 += 32) {
            bf16x8 ax = ldg8(xr + k0);
            aR = __builtin_amdgcn_mfma_f32_16x16x32_bf16(ax, ldg8(wiR + k0),          aR, 0, 0, 0);
            aZ = __builtin_amdgcn_mfma_f32_16x16x32_bf16(ax, ldg8(wiR + DHDH + k0),   aZ, 0, 0, 0);
            aN = __builtin_amdgcn_mfma_f32_16x16x32_bf16(ax, ldg8(wiR + 2*DHDH + k0), aN, 0, 0, 0);
        }
        red_store(red, 0, w, lane, aR);
        red_store(red, 1, w, lane, aZ);
        red_store(red, 2, w, lane, aN);
        __syncthreads();
        giR[s] = red_sum(red, 0, wb, kc, lane);
        giZ[s] = red_sum(red, 1, wb, kc, lane);
        giN[s] = red_sum(red, 2, wb, kc, lane);
        __syncthreads();
    }

    int ph = 0;
    gridbar(bar, ph++);

    // ---- 4 steps x 2 layers, K-split 4x128 per matmul
    int cur0 = 0, cur1 = 0;
#pragma unroll
    for (int s = 0; s < NSTEP; ++s) {
        // layer 0: gh = h0 @ w_hh0^T (3 gates); gi precomputed
        {
            const bf16* hr  = h0b + (size_t)cur0 * HSZ + (size_t)(m0 + lr) * DH + kc * 128 + q * 8;
            const bf16* whR = w0h + (size_t)(d0 + lr) * DH + kc * 128 + q * 8;
            f32x4 aR = {0,0,0,0}, aZ = {0,0,0,0}, aN = {0,0,0,0};
#pragma unroll
            for (int k0 = 0; k0 < 128; k0 += 32) {
                bf16x8 ah = ldg8(hr + k0);
                aR = __builtin_amdgcn_mfma_f32_16x16x32_bf16(ah, ldg8(whR + k0),          aR, 0, 0, 0);
                aZ = __builtin_amdgcn_mfma_f32_16x16x32_bf16(ah, ldg8(whR + DHDH + k0),   aZ, 0, 0, 0);
                aN = __builtin_amdgcn_mfma_f32_16x16x32_bf16(ah, ldg8(whR + 2*DHDH + k0), aN, 0, 0, 0);
            }
            red_store(red, 0, w, lane, aR);
            red_store(red, 1, w, lane, aZ);
            red_store(red, 2, w, lane, aN);
            __syncthreads();
            float ghR = red_sum(red, 0, wb, kc, lane);
            float ghZ = red_sum(red, 1, wb, kc, lane);
            float ghN = red_sum(red, 2, wb, kc, lane);
            __syncthreads();
            float rg = sigmf(giR[s] + ghR + bR0);
            float zg = sigmf(giZ[s] + ghZ + bZ0);
            float ng = tanhf(giN[s] + biN0 + rg * (ghN + bhN0));
            h0st = (1.f - zg) * ng + zg * h0st;
            h0b[(cur0 ^ 1) * HSZ + row * DH + d] = __float2bfloat16(h0st);
            cur0 ^= 1;
        }
        gridbar(bar, ph++);
        // layer 1: 6 matmul-gates (h1 @ w_hh1^T and h0_new @ w_ih1^T)
        {
            const bf16* h1r = h1b + (size_t)cur1 * HSZ + (size_t)(m0 + lr) * DH + kc * 128 + q * 8;
            const bf16* h0r = h0b + (size_t)cur0 * HSZ + (size_t)(m0 + lr) * DH + kc * 128 + q * 8;
            const bf16* whR = w1h + (size_t)(d0 + lr) * DH + kc * 128 + q * 8;
            const bf16* wiR = w1i + (size_t)(d0 + lr) * DH + kc * 128 + q * 8;
            f32x4 R = {0,0,0,0}, Z = {0,0,0,0}, iN = {0,0,0,0}, aN = {0,0,0,0};
#pragma unroll
            for (int k0 = 0; k0 < 128; k0 += 32) {
                bf16x8 a1 = ldg8(h1r + k0);
                bf16x8 a0 = ldg8(h0r + k0);
                R  = __builtin_amdgcn_mfma_f32_16x16x32_bf16(a1, ldg8(whR + k0),          R,  0, 0, 0);
                R  = __builtin_amdgcn_mfma_f32_16x16x32_bf16(a0, ldg8(wiR + k0),          R,  0, 0, 0);
                Z  = __builtin_amdgcn_mfma_f32_16x16x32_bf16(a1, ldg8(whR + DHDH + k0),   Z,  0, 0, 0);
                Z  = __builtin_amdgcn_mfma_f32_16x16x32_bf16(a0, ldg8(wiR + DHDH + k0),   Z,  0, 0, 0);
                aN = __builtin_amdgcn_mfma_f32_16x16x32_bf16(a1, ldg8(whR + 2*DHDH + k0), aN, 0, 0, 0);
                iN = __builtin_amdgcn_mfma_f32_16x16x32_bf16(a0, ldg8(wiR + 2*DHDH + k0), iN, 0, 0, 0);
            }
            red_store(red, 0, w, lane, R);
            red_store(red, 1, w, lane, Z);
            red_store(red, 2, w, lane, iN);
            red_store(red, 3, w, lane, aN);
            __syncthreads();
            float SR  = red_sum(red, 0, wb, kc, lane);
            float SZ  = red_sum(red, 1, wb, kc, lane);
            float SiN = red_sum(red, 2, wb, kc, lane);
            float SaN = red_sum(red, 3, wb, kc, lane);
            __syncthreads();
            float rg = sigmf(SR + bR1);
            float zg = sigmf(SZ + bZ1);
            float ng = tanhf(SiN + biN1 + rg * (SaN + bhN1));
            h1st = (1.f - zg) * ng + zg * h1st;
            bf16 hvb = __float2bfloat16(h1st);
            h1b[(cur1 ^ 1) * HSZ + row * DH + d] = hvb;
            hbig[(size_t)(row * NSTEP + s) * DH + d] = hvb;
            cur1 ^= 1;
        }
        if (s < NSTEP - 1) gridbar(bar, ph++);
    }
}

// ---------------------------------------------------------------------------
// k_logits: out(256x50257 f32) = Hbig(256x512 bf16) @ out_w(50257x512 f32)^T
// 32x32x16 MFMA; block = 64 cols x 4 waves; wave = 4 m-tiles x 32 n-cols
// (acc = 64 VGPRs -> ~2x occupancy vs 8-m-tile version). Both m-half waves
// read the same out_w rows (L1/L2 hit), so HBM traffic is unchanged.
// A staged per 64-k chunk in XOR-swizzled LDS: conflict-free.
// ---------------------------------------------------------------------------
__global__ __launch_bounds__(256) void k_logits(
    const bf16* __restrict__ hbig, const float* __restrict__ outw, float* __restrict__ out)
{
    __shared__ __align__(16) bf16 sA[256 * 64];
    int t = threadIdx.x, w = t >> 6, lane = t & 63;
    int l32 = lane & 31, e = lane >> 5;
    int mh = w >> 1;                         // m-half (rows 0..127 / 128..255)
    int n = blockIdx.x * 64 + (w & 1) * 32 + l32;
    int nr = n < VOC ? n : VOC - 1;
    const float* brow = outw + (size_t)nr * DH;

    f32x16 acc[4];
#pragma unroll
    for (int i = 0; i < 4; ++i)
#pragma unroll
        for (int j = 0; j < 16; ++j) acc[i][j] = 0.f;

    for (int k0 = 0; k0 < DH; k0 += 64) {
        // stage A[0:256][k0:k0+64] -> LDS, XOR-swizzled 16B groups
#pragma unroll
        for (int i = 0; i < 8; ++i) {
            int c = i * 256 + t;
            int m = c >> 3, j = c & 7;
            *reinterpret_cast<bf16x8*>(&sA[m * 64 + ((j ^ (m & 7)) << 3)]) =
                ldg8(hbig + (size_t)m * DH + k0 + j * 8);
        }
        __syncthreads();
#pragma unroll
        for (int kk = 0; kk < 64; kk += 16) {
            bf16x8 bfrag = cvt8(brow + k0 + kk + e * 8);
            int g = (kk >> 3) + e;
#pragma unroll
            for (int mt = 0; mt < 4; ++mt) {
                int r = (mh * 4 + mt) * 32 + l32;
                bf16x8 afrag = *reinterpret_cast<const bf16x8*>(
                    &sA[r * 64 + ((g ^ (r & 7)) << 3)]);
                acc[mt] = __builtin_amdgcn_mfma_f32_32x32x16_bf16(afrag, bfrag, acc[mt], 0, 0, 0);
            }
        }
        __syncthreads();
    }
    if (n < VOC) {
#pragma unroll
        for (int mt = 0; mt < 4; ++mt)
#pragma unroll
            for (int reg = 0; reg < 16; ++reg) {
                int m = (mh * 4 + mt) * 32 + (reg & 3) + 8 * (reg >> 2) + 4 * e;
                out[(size_t)m * VOC + n] = acc[mt][reg];
            }
    }
}

// ---------------------------------------------------------------------------
extern "C" void kernel_launch(void* const* d_in, const int* in_sizes, int n_in,
                              void* d_out, int out_size, void* d_ws, size_t ws_size,
                              hipStream_t stream) {
    const float* hs   = (const float*)d_in[0];
    const int*   tids = (const int*)d_in[1];
    const float* ipw  = (const float*)d_in[2];
    const float* ipb  = (const float*)d_in[3];
    const float* wih0 = (const float*)d_in[4];
    const float* whh0 = (const float*)d_in[5];
    const float* bih0 = (const float*)d_in[6];
    const float* bhh0 = (const float*)d_in[7];
    const float* wih1 = (const float*)d_in[8];
    const float* whh1 = (const float*)d_in[9];
    const float* bih1 = (const float*)d_in[10];
    const float* bhh1 = (const float*)d_in[11];
    const float* embed = (const float*)d_in[12];
    const float* outw  = (const float*)d_in[13];
    float* out = (float*)d_out;

    char* ws = (char*)d_ws;
    int*  bar  = (int*) (ws + 0);          // 64 ints, memset to 0 below
    bf16* hsb  = (bf16*)(ws + 1024);       // 64x4096        (524288 B)
    bf16* ipwb = (bf16*)(ws + 525312);     // 512x4096       (4194304 B)
    bf16* w0i  = (bf16*)(ws + 4719616);    // 1536x512       (1572864 B)
    bf16* w0h  = (bf16*)(ws + 6292480);
    bf16* w1i  = (bf16*)(ws + 7865344);
    bf16* w1h  = (bf16*)(ws + 9438208);
    bf16* xemb = (bf16*)(ws + 11011072);   // 3x64x512       (196608 B)
    bf16* h0b  = (bf16*)(ws + 11207680);   // [2][64x512] bf16 (131072 B)
    bf16* h1b  = (bf16*)(ws + 11338752);
    bf16* hbig = (bf16*)(ws + 11469824);   // 256x512 bf16, row m = b*4+s

    hipMemsetAsync(bar, 0, 256, stream);

    k_prep<<<1368, 512, 0, stream>>>(hs, ipw, wih0, whh0, wih1, whh1, embed, tids,
                                     hsb, ipwb, w0i, w0h, w1i, w1h, xemb);

    k_fused<<<NBLK_FUSED, 512, 0, stream>>>(hsb, ipwb, ipb,
                                            w0i, w0h, bih0, bhh0,
                                            w1i, w1h, bih1, bhh1,
                                            xemb, h0b, h1b, hbig, bar);

    k_logits<<<(VOC + 63) / 64, 256, 0, stream>>>(hbig, outw, out);
}